// Round 15
// baseline (222.707 us; speedup 1.0000x reference)
//
#include <hip/hip_runtime.h>
#include <hip/hip_bf16.h>

// GraphSAGE 2-layer + classifier on MI355X.
// R15 = R11 baseline (200.3us) + 4-gather-chain agg1 (deconfounded from R14's
// nt-store-on-x8 poison, which evicted the gather table from L2 and regressed
// agg1). All nt hints removed; CAP back to 128. Scatter accepted as-is after
// three attacks (R12 partition: FETCH doubled; R14 nt: WRITE unchanged) —
// combo ~50us is atomic-latency + cross-XCD partial-line bound, not bytes.
// 5 dispatches:
//   memset(cnt) -> combo(cvt + W1 trans + Wa/Wb/bc2 + fill)
//   -> agg1(fp8) -> gemm1(->p,q fused) -> agg_out(->out)
// Layer-2 algebra (R10): out = agg16(h@Wa) + h@Wb + bc2, Wa/Wb = W2{l,r}@Wc.

#define FEAT 256
#define NCLS 16
#define ZPAD 264   // 256 + 8 bf16 pad
#define CAP  128   // bucket capacity per node (deg~Poisson(32), P(>128)~1e-50)

typedef __bf16 bf16x8 __attribute__((ext_vector_type(8)));
typedef __bf16 bf16x4 __attribute__((ext_vector_type(4)));
typedef float  f32x4  __attribute__((ext_vector_type(4)));
typedef float  f32x2  __attribute__((ext_vector_type(2)));
typedef unsigned int uint4v __attribute__((ext_vector_type(4)));

// ---------------- combo: cvt + W1 transposes + Wa/Wb/bc2 + bucket fill ----------------
// Block ranges (1D grid):
//   [0, nb_cvt)     : x -> xb (bf16) + x8 (fp8 e4m3)
//   [+512)          : W1{l,r}T[n][k] = W[k][n] (bf16)
//   [+32)           : WaT/WbT[c][k] = sum_m W2{l,r}[k][m]*Wc[m][c]
//   [+1)            : bc2[c] = sum_k b2[k]*Wc[k][c] + bc[c]
//   [rest, nb_edge) : bucket fill, 2 edges/thread (cnt pre-zeroed by memset)

__global__ void combo_kernel(const float* __restrict__ x,
                             const float* __restrict__ W1l, const float* __restrict__ W1r,
                             const float* __restrict__ W2l, const float* __restrict__ W2r,
                             const float* __restrict__ Wc, const float* __restrict__ b2,
                             const float* __restrict__ bc,
                             const int* __restrict__ src, const int* __restrict__ dst,
                             __bf16* __restrict__ xb, unsigned char* __restrict__ x8,
                             __bf16* __restrict__ W1lT, __bf16* __restrict__ W1rT,
                             __bf16* __restrict__ WaT, __bf16* __restrict__ WbT,
                             float* __restrict__ bc2,
                             int* __restrict__ cnt, unsigned short* __restrict__ bucket,
                             int n4, int E, int nb_cvt) {
    int t = threadIdx.x;
    int bx = blockIdx.x;
    if (bx < nb_cvt) {
        int i = bx * 256 + t;
        if (i < n4) {
            f32x4 v = ((const f32x4*)x)[i];
            bf16x4 o;
            #pragma unroll
            for (int j = 0; j < 4; ++j) o[j] = (__bf16)v[j];
            ((bf16x4*)xb)[i] = o;
            int pk = 0;
            pk = __builtin_amdgcn_cvt_pk_fp8_f32(v[0], v[1], pk, false);
            pk = __builtin_amdgcn_cvt_pk_fp8_f32(v[2], v[3], pk, true);
            ((int*)x8)[i] = pk;
        }
    } else if (bx < nb_cvt + 512) {
        int b = bx - nb_cvt;
        int w = b >> 8, nn = b & 255;
        const float* W = w ? W1r : W1l;
        __bf16* WT = w ? W1rT : W1lT;
        WT[nn * FEAT + t] = (__bf16)W[t * FEAT + nn];
    } else if (bx < nb_cvt + 512 + 32) {
        int b = bx - nb_cvt - 512;       // 0..31
        int c = b & 15;
        const float* W = (b < 16) ? W2l : W2r;   // thread t = row k
        __bf16* WT = (b < 16) ? WaT : WbT;
        float s = 0.f;
        #pragma unroll 4
        for (int m = 0; m < FEAT; ++m)
            s += W[t * FEAT + m] * Wc[m * NCLS + c];
        WT[c * FEAT + t] = (__bf16)s;
    } else if (bx == nb_cvt + 512 + 32) {
        if (t < NCLS) {
            float s = 0.f;
            for (int k = 0; k < FEAT; ++k) s += b2[k] * Wc[k * NCLS + t];
            bc2[t] = s + bc[t];
        }
    } else {
        int idx = (bx - nb_cvt - 512 - 33) * 256 + t;
        int e2 = idx * 2;
        if (e2 < E) {
            int2 sv = *(const int2*)(src + e2);
            int2 dv = *(const int2*)(dst + e2);
            int p0 = atomicAdd(&cnt[dv.x], 1);
            if (p0 < CAP) bucket[dv.x * CAP + p0] = (unsigned short)sv.x;
            if (e2 + 1 < E) {
                int p1 = atomicAdd(&cnt[dv.y], 1);
                if (p1 < CAP) bucket[dv.y * CAP + p1] = (unsigned short)sv.y;
            }
        }
    }
}

// ---------------- agg1: fp8 gather, one wave per node, 4 rows in flight ----
// Quad q handles bucket entries q, q+4, ...; 4 independent gather chains.
// Lane reads 16 feats (dwordx4); shfl_xor(16,32) merges quads.

__global__ __launch_bounds__(256) void agg_fp8_kernel(
    const unsigned char* __restrict__ t8, const int* __restrict__ cnt,
    const unsigned short* __restrict__ bucket, __bf16* __restrict__ out, int n)
{
    int wave = threadIdx.x >> 6;
    int node = blockIdx.x * 4 + wave;
    if (node >= n) return;
    int lane = threadIdx.x & 63;
    int quad = lane >> 4, l16 = lane & 15;
    int c = cnt[node];
    int deg = c < CAP ? c : CAP;
    const unsigned short* lst = bucket + node * CAP;

    f32x4 s[4][4];   // [chain][wordgroup]
    #pragma unroll
    for (int ch = 0; ch < 4; ++ch)
        #pragma unroll
        for (int w = 0; w < 4; ++w) s[ch][w] = (f32x4){0.f, 0.f, 0.f, 0.f};

    int e = quad;
    for (; e + 12 < deg; e += 16) {
        int j0 = lst[e], j1 = lst[e + 4], j2 = lst[e + 8], j3 = lst[e + 12];
        uint4v u0 = *(const uint4v*)(t8 + (size_t)j0 * FEAT + l16 * 16);
        uint4v u1 = *(const uint4v*)(t8 + (size_t)j1 * FEAT + l16 * 16);
        uint4v u2 = *(const uint4v*)(t8 + (size_t)j2 * FEAT + l16 * 16);
        uint4v u3 = *(const uint4v*)(t8 + (size_t)j3 * FEAT + l16 * 16);
        #pragma unroll
        for (int w = 0; w < 4; ++w) {
            f32x2 lo, hi;
            lo = __builtin_amdgcn_cvt_pk_f32_fp8(u0[w], false);
            hi = __builtin_amdgcn_cvt_pk_f32_fp8(u0[w], true);
            s[0][w][0] += lo[0]; s[0][w][1] += lo[1]; s[0][w][2] += hi[0]; s[0][w][3] += hi[1];
            lo = __builtin_amdgcn_cvt_pk_f32_fp8(u1[w], false);
            hi = __builtin_amdgcn_cvt_pk_f32_fp8(u1[w], true);
            s[1][w][0] += lo[0]; s[1][w][1] += lo[1]; s[1][w][2] += hi[0]; s[1][w][3] += hi[1];
            lo = __builtin_amdgcn_cvt_pk_f32_fp8(u2[w], false);
            hi = __builtin_amdgcn_cvt_pk_f32_fp8(u2[w], true);
            s[2][w][0] += lo[0]; s[2][w][1] += lo[1]; s[2][w][2] += hi[0]; s[2][w][3] += hi[1];
            lo = __builtin_amdgcn_cvt_pk_f32_fp8(u3[w], false);
            hi = __builtin_amdgcn_cvt_pk_f32_fp8(u3[w], true);
            s[3][w][0] += lo[0]; s[3][w][1] += lo[1]; s[3][w][2] += hi[0]; s[3][w][3] += hi[1];
        }
    }
    for (; e < deg; e += 4) {
        int j = lst[e];
        uint4v u = *(const uint4v*)(t8 + (size_t)j * FEAT + l16 * 16);
        #pragma unroll
        for (int w = 0; w < 4; ++w) {
            f32x2 lo = __builtin_amdgcn_cvt_pk_f32_fp8(u[w], false);
            f32x2 hi = __builtin_amdgcn_cvt_pk_f32_fp8(u[w], true);
            s[0][w][0] += lo[0]; s[0][w][1] += lo[1]; s[0][w][2] += hi[0]; s[0][w][3] += hi[1];
        }
    }

    #pragma unroll
    for (int w = 0; w < 4; ++w)
        #pragma unroll
        for (int j = 0; j < 4; ++j) {
            float v = (s[0][w][j] + s[1][w][j]) + (s[2][w][j] + s[3][w][j]);
            v += __shfl_xor(v, 16, 64);
            v += __shfl_xor(v, 32, 64);
            s[0][w][j] = v;
        }

    float inv = (c > 0) ? 1.0f / (float)c : 0.0f;
    bf16x4 o;
    #pragma unroll
    for (int j = 0; j < 4; ++j) o[j] = (__bf16)(s[0][quad][j] * inv);
    *(bf16x4*)(out + (size_t)node * FEAT + l16 * 16 + quad * 4) = o;
}

// ---------------- gemm1 + fused pq ----------------
// Main: h = relu(A1@B1 + A2@B2 + b1) -> LDS tile (bf16, never to global).
// Epilogue: waves 0/1 compute p = h@Wa (bf16), q = h@Wb + bc2 (f32) via MFMA.
// MFMA layouts (HW-verified m89/m91): A: row=lane&15, k=quad*8+j;
// B: col=lane&15, k=quad*8+j; C/D: col=lane&15, row=quad*4+reg.

__global__ __launch_bounds__(256) void gemm1_kernel(
    const __bf16* __restrict__ A1, const __bf16* __restrict__ A2,
    const __bf16* __restrict__ B1T, const __bf16* __restrict__ B2T,
    const float* __restrict__ bias,
    const __bf16* __restrict__ WaT, const __bf16* __restrict__ WbT,
    const float* __restrict__ bc2,
    __bf16* __restrict__ pb, float* __restrict__ q, int M)
{
    __shared__ __align__(16) __bf16 tile[32][ZPAD];   // 16.5 KB

    int m0   = blockIdx.x * 32;
    int lane = threadIdx.x & 63;
    int wave = threadIdx.x >> 6;
    int l16  = lane & 15, quad = lane >> 4;

    f32x4 acc[2][4];
    #pragma unroll
    for (int a = 0; a < 2; ++a)
        #pragma unroll
        for (int b = 0; b < 4; ++b) acc[a][b] = (f32x4){0.f, 0.f, 0.f, 0.f};

    int arow[2];
    #pragma unroll
    for (int mt = 0; mt < 2; ++mt) {
        int r = m0 + mt * 16 + l16;
        arow[mt] = (r < M) ? r : (M - 1);
    }
    int nbase = wave * 64;

    for (int pass = 0; pass < 2; ++pass) {
        const __bf16* A  = pass ? A2 : A1;
        const __bf16* BT = pass ? B2T : B1T;
        #pragma unroll 2
        for (int kk = 0; kk < 8; ++kk) {
            int k0 = kk * 32 + quad * 8;
            bf16x8 af[2], bfm[4];
            #pragma unroll
            for (int mt = 0; mt < 2; ++mt)
                af[mt] = *(const bf16x8*)(A + (size_t)arow[mt] * FEAT + k0);
            #pragma unroll
            for (int nt = 0; nt < 4; ++nt)
                bfm[nt] = *(const bf16x8*)(BT + (size_t)(nbase + nt * 16 + l16) * FEAT + k0);
            #pragma unroll
            for (int mt = 0; mt < 2; ++mt)
                #pragma unroll
                for (int nt = 0; nt < 4; ++nt)
                    acc[mt][nt] = __builtin_amdgcn_mfma_f32_16x16x32_bf16(
                        af[mt], bfm[nt], acc[mt][nt], 0, 0, 0);
        }
    }

    // h tile (+bias, relu) -> LDS
    #pragma unroll
    for (int nt = 0; nt < 4; ++nt) {
        int col = nbase + nt * 16 + l16;
        float bv = bias[col];
        #pragma unroll
        for (int mt = 0; mt < 2; ++mt) {
            int lr = mt * 16 + quad * 4;
            #pragma unroll
            for (int r = 0; r < 4; ++r) {
                float v = acc[mt][nt][r] + bv;
                tile[lr + r][col] = (__bf16)(v > 0.f ? v : 0.f);
            }
        }
    }
    __syncthreads();

    // fused pq: waves 0/1, 16 rows each; A from LDS, B from L2-hot Wa/Wb
    if (wave < 2) {
        int lr = wave * 16 + l16;
        f32x4 ap = {0.f, 0.f, 0.f, 0.f}, aq = {0.f, 0.f, 0.f, 0.f};
        #pragma unroll
        for (int kk = 0; kk < 8; ++kk) {
            int k0 = kk * 32 + quad * 8;
            bf16x8 a  = *(const bf16x8*)(&tile[lr][k0]);
            bf16x8 ba = *(const bf16x8*)(WaT + (size_t)l16 * FEAT + k0);
            bf16x8 bb = *(const bf16x8*)(WbT + (size_t)l16 * FEAT + k0);
            ap = __builtin_amdgcn_mfma_f32_16x16x32_bf16(a, ba, ap, 0, 0, 0);
            aq = __builtin_amdgcn_mfma_f32_16x16x32_bf16(a, bb, aq, 0, 0, 0);
        }
        float qv = bc2[l16];
        #pragma unroll
        for (int r = 0; r < 4; ++r) {
            int row = m0 + wave * 16 + quad * 4 + r;
            if (row < M) {
                pb[(size_t)row * NCLS + l16] = (__bf16)ap[r];
                q[(size_t)row * NCLS + l16] = aq[r] + qv;
            }
        }
    }
}

// ---------------- agg_out: out = mean_j p[j] + q (16 feats) ----------------
// One wave per node; quad q takes bucket entries q, q+4, ... (2 in flight);
// lane l16 holds feature l16; shfl merge; quad 0 writes.

__global__ __launch_bounds__(256) void agg_out_kernel(
    const __bf16* __restrict__ pb, const float* __restrict__ q,
    const int* __restrict__ cnt, const unsigned short* __restrict__ bucket,
    float* __restrict__ out, int n)
{
    int wave = threadIdx.x >> 6;
    int node = blockIdx.x * 4 + wave;
    if (node >= n) return;
    int lane = threadIdx.x & 63;
    int quad = lane >> 4, l16 = lane & 15;
    int c = cnt[node];
    int deg = c < CAP ? c : CAP;
    const unsigned short* lst = bucket + node * CAP;

    float s0 = 0.f, s1 = 0.f;
    int e = quad;
    for (; e + 4 < deg; e += 8) {
        int j0 = lst[e], j1 = lst[e + 4];
        s0 += (float)pb[(size_t)j0 * NCLS + l16];
        s1 += (float)pb[(size_t)j1 * NCLS + l16];
    }
    if (e < deg) s0 += (float)pb[(size_t)lst[e] * NCLS + l16];

    float v = s0 + s1;
    v += __shfl_xor(v, 16, 64);
    v += __shfl_xor(v, 32, 64);

    if (quad == 0) {
        float inv = (c > 0) ? 1.0f / (float)c : 0.0f;
        out[(size_t)node * NCLS + l16] = v * inv + q[(size_t)node * NCLS + l16];
    }
}

// ---------------- launch ----------------

extern "C" void kernel_launch(void* const* d_in, const int* in_sizes, int n_in,
                              void* d_out, int out_size, void* d_ws, size_t ws_size,
                              hipStream_t stream) {
    const float* x   = (const float*)d_in[0];
    const int*   ei  = (const int*)d_in[1];
    const float* W1l = (const float*)d_in[2];
    const float* b1  = (const float*)d_in[3];
    const float* W1r = (const float*)d_in[4];
    const float* W2l = (const float*)d_in[5];
    const float* b2  = (const float*)d_in[6];
    const float* W2r = (const float*)d_in[7];
    const float* Wc  = (const float*)d_in[8];
    const float* bc  = (const float*)d_in[9];
    float* out = (float*)d_out;

    const int n = in_sizes[0] / FEAT;   // 20000
    const int E = in_sizes[1] / 2;      // 640000
    const int* srcp = ei;
    const int* dstp = ei + E;

    char* p = (char*)d_ws;
    auto alloc = [&](size_t bytes) { char* r = p; p += (bytes + 511) & ~511ull; return r; };
    int* cnt       = (int*)alloc((size_t)n * 4);
    unsigned short* bucket = (unsigned short*)alloc((size_t)n * CAP * 2);   // 5.12 MB
    __bf16* W1lT   = (__bf16*)alloc((size_t)FEAT * FEAT * 2);
    __bf16* W1rT   = (__bf16*)alloc((size_t)FEAT * FEAT * 2);
    __bf16* WaT    = (__bf16*)alloc((size_t)NCLS * FEAT * 2);
    __bf16* WbT    = (__bf16*)alloc((size_t)NCLS * FEAT * 2);
    float*  bc2    = (float*)alloc((size_t)NCLS * 4);
    __bf16* xb     = (__bf16*)alloc((size_t)n * FEAT * 2);
    unsigned char* x8 = (unsigned char*)alloc((size_t)n * FEAT);
    __bf16* aggb   = (__bf16*)alloc((size_t)n * FEAT * 2);
    __bf16* pb     = (__bf16*)alloc((size_t)n * NCLS * 2);
    float*  qb     = (float*)alloc((size_t)n * NCLS * 4);

    int n4 = n * FEAT / 4;
    int nb_cvt = (n4 + 255) / 256;          // 5000
    int nb_edge = (E + 511) / 512;          // 1250 (2 edges/thread)

    // cnt = 0 (80 KB)
    hipMemsetAsync(cnt, 0, (size_t)n * 4, stream);

    // combo: cvt + W1 transposes + Wa/Wb/bc2 + bucket fill
    combo_kernel<<<nb_cvt + 512 + 32 + 1 + nb_edge, 256, 0, stream>>>(
        x, W1l, W1r, W2l, W2r, Wc, b2, bc, srcp, dstp,
        xb, x8, W1lT, W1rT, WaT, WbT, bc2, cnt, bucket, n4, E, nb_cvt);

    // layer 1 + fused pq
    agg_fp8_kernel<<<(n + 3) / 4, 256, 0, stream>>>(x8, cnt, bucket, aggb, n);
    gemm1_kernel<<<(n + 31) / 32, 256, 0, stream>>>(aggb, xb, W1lT, W1rT, b1,
                                                    WaT, WbT, bc2, pb, qb, n);

    // layer-2 aggregation -> logits
    agg_out_kernel<<<(n + 3) / 4, 256, 0, stream>>>(pb, qb, cnt, bucket, out, n);
}

// Round 16
// 208.342 us; speedup vs baseline: 1.0689x; 1.0689x over previous
//
#include <hip/hip_runtime.h>
#include <hip/hip_bf16.h>

// GraphSAGE 2-layer + classifier on MI355X.
// R16 = exact revert to R11 (session-best, 200.3us measured). R12 (partitioned
// scatter), R13/R14 (nt hints, CAP 96), R15 (4-chain gather MLP) all regressed
// or were neutral with counter-evidence refuting each theory; R15 also showed
// ~30% session noise on identical combo code, so this re-measures the R11
// baseline to deconfound.
// 5 dispatches:
//   memset(cnt) -> combo(cvt + W1 trans + Wa/Wb/bc2 + fill)
//   -> agg1(fp8) -> gemm1(->p,q fused) -> agg_out(->out)
// Layer-2 algebra (R10): out = agg16(h@Wa) + h@Wb + bc2, Wa/Wb = W2{l,r}@Wc.

#define FEAT 256
#define NCLS 16
#define ZPAD 264   // 256 + 8 bf16 pad
#define CAP  128   // bucket capacity per node (deg~Poisson(32), P(>128)~1e-50)

typedef __bf16 bf16x8 __attribute__((ext_vector_type(8)));
typedef __bf16 bf16x4 __attribute__((ext_vector_type(4)));
typedef float  f32x4  __attribute__((ext_vector_type(4)));
typedef float  f32x2  __attribute__((ext_vector_type(2)));
typedef unsigned int uint4v __attribute__((ext_vector_type(4)));

// ---------------- combo: cvt + W1 transposes + Wa/Wb/bc2 + bucket fill ----------------
// Block ranges (1D grid):
//   [0, nb_cvt)     : x -> xb (bf16) + x8 (fp8 e4m3)
//   [+512)          : W1{l,r}T[n][k] = W[k][n] (bf16)
//   [+32)           : WaT/WbT[c][k] = sum_m W2{l,r}[k][m]*Wc[m][c]
//   [+1)            : bc2[c] = sum_k b2[k]*Wc[k][c] + bc[c]
//   [rest, nb_edge) : bucket fill, 2 edges/thread (cnt pre-zeroed by memset)

__global__ void combo_kernel(const float* __restrict__ x,
                             const float* __restrict__ W1l, const float* __restrict__ W1r,
                             const float* __restrict__ W2l, const float* __restrict__ W2r,
                             const float* __restrict__ Wc, const float* __restrict__ b2,
                             const float* __restrict__ bc,
                             const int* __restrict__ src, const int* __restrict__ dst,
                             __bf16* __restrict__ xb, unsigned char* __restrict__ x8,
                             __bf16* __restrict__ W1lT, __bf16* __restrict__ W1rT,
                             __bf16* __restrict__ WaT, __bf16* __restrict__ WbT,
                             float* __restrict__ bc2,
                             int* __restrict__ cnt, unsigned short* __restrict__ bucket,
                             int n4, int E, int nb_cvt) {
    int t = threadIdx.x;
    int bx = blockIdx.x;
    if (bx < nb_cvt) {
        int i = bx * 256 + t;
        if (i < n4) {
            f32x4 v = ((const f32x4*)x)[i];
            bf16x4 o;
            #pragma unroll
            for (int j = 0; j < 4; ++j) o[j] = (__bf16)v[j];
            ((bf16x4*)xb)[i] = o;
            int pk = 0;
            pk = __builtin_amdgcn_cvt_pk_fp8_f32(v[0], v[1], pk, false);
            pk = __builtin_amdgcn_cvt_pk_fp8_f32(v[2], v[3], pk, true);
            ((int*)x8)[i] = pk;
        }
    } else if (bx < nb_cvt + 512) {
        int b = bx - nb_cvt;
        int w = b >> 8, nn = b & 255;
        const float* W = w ? W1r : W1l;
        __bf16* WT = w ? W1rT : W1lT;
        WT[nn * FEAT + t] = (__bf16)W[t * FEAT + nn];
    } else if (bx < nb_cvt + 512 + 32) {
        int b = bx - nb_cvt - 512;       // 0..31
        int c = b & 15;
        const float* W = (b < 16) ? W2l : W2r;   // thread t = row k
        __bf16* WT = (b < 16) ? WaT : WbT;
        float s = 0.f;
        #pragma unroll 4
        for (int m = 0; m < FEAT; ++m)
            s += W[t * FEAT + m] * Wc[m * NCLS + c];
        WT[c * FEAT + t] = (__bf16)s;
    } else if (bx == nb_cvt + 512 + 32) {
        if (t < NCLS) {
            float s = 0.f;
            for (int k = 0; k < FEAT; ++k) s += b2[k] * Wc[k * NCLS + t];
            bc2[t] = s + bc[t];
        }
    } else {
        int idx = (bx - nb_cvt - 512 - 33) * 256 + t;
        int e2 = idx * 2;
        if (e2 < E) {
            int2 sv = *(const int2*)(src + e2);
            int2 dv = *(const int2*)(dst + e2);
            int p0 = atomicAdd(&cnt[dv.x], 1);
            if (p0 < CAP) bucket[dv.x * CAP + p0] = (unsigned short)sv.x;
            if (e2 + 1 < E) {
                int p1 = atomicAdd(&cnt[dv.y], 1);
                if (p1 < CAP) bucket[dv.y * CAP + p1] = (unsigned short)sv.y;
            }
        }
    }
}

// ---------------- agg1: fp8 gather, one wave per node ----------------
// Quad q handles bucket entries q, q+4, ...; 2 rows in flight per quad.
// Lane reads 16 feats (dwordx4); shfl_xor(16,32) merges quads.

__global__ __launch_bounds__(256) void agg_fp8_kernel(
    const unsigned char* __restrict__ t8, const int* __restrict__ cnt,
    const unsigned short* __restrict__ bucket, __bf16* __restrict__ out, int n)
{
    int wave = threadIdx.x >> 6;
    int node = blockIdx.x * 4 + wave;
    if (node >= n) return;
    int lane = threadIdx.x & 63;
    int quad = lane >> 4, l16 = lane & 15;
    int c = cnt[node];
    int deg = c < CAP ? c : CAP;
    const unsigned short* lst = bucket + node * CAP;

    f32x4 s0[4], s1[4];
    #pragma unroll
    for (int w = 0; w < 4; ++w) { s0[w] = (f32x4){0.f,0.f,0.f,0.f}; s1[w] = (f32x4){0.f,0.f,0.f,0.f}; }

    int e = quad;
    for (; e + 4 < deg; e += 8) {
        int j0 = lst[e], j1 = lst[e + 4];
        uint4v u0 = *(const uint4v*)(t8 + (size_t)j0 * FEAT + l16 * 16);
        uint4v u1 = *(const uint4v*)(t8 + (size_t)j1 * FEAT + l16 * 16);
        #pragma unroll
        for (int w = 0; w < 4; ++w) {
            f32x2 lo0 = __builtin_amdgcn_cvt_pk_f32_fp8(u0[w], false);
            f32x2 hi0 = __builtin_amdgcn_cvt_pk_f32_fp8(u0[w], true);
            s0[w][0] += lo0[0]; s0[w][1] += lo0[1]; s0[w][2] += hi0[0]; s0[w][3] += hi0[1];
            f32x2 lo1 = __builtin_amdgcn_cvt_pk_f32_fp8(u1[w], false);
            f32x2 hi1 = __builtin_amdgcn_cvt_pk_f32_fp8(u1[w], true);
            s1[w][0] += lo1[0]; s1[w][1] += lo1[1]; s1[w][2] += hi1[0]; s1[w][3] += hi1[1];
        }
    }
    if (e < deg) {
        int j = lst[e];
        uint4v u = *(const uint4v*)(t8 + (size_t)j * FEAT + l16 * 16);
        #pragma unroll
        for (int w = 0; w < 4; ++w) {
            f32x2 lo = __builtin_amdgcn_cvt_pk_f32_fp8(u[w], false);
            f32x2 hi = __builtin_amdgcn_cvt_pk_f32_fp8(u[w], true);
            s0[w][0] += lo[0]; s0[w][1] += lo[1]; s0[w][2] += hi[0]; s0[w][3] += hi[1];
        }
    }

    #pragma unroll
    for (int w = 0; w < 4; ++w)
        #pragma unroll
        for (int j = 0; j < 4; ++j) {
            float v = s0[w][j] + s1[w][j];
            v += __shfl_xor(v, 16, 64);
            v += __shfl_xor(v, 32, 64);
            s0[w][j] = v;
        }

    float inv = (c > 0) ? 1.0f / (float)c : 0.0f;
    bf16x4 o;
    #pragma unroll
    for (int j = 0; j < 4; ++j) o[j] = (__bf16)(s0[quad][j] * inv);
    *(bf16x4*)(out + (size_t)node * FEAT + l16 * 16 + quad * 4) = o;
}

// ---------------- gemm1 + fused pq ----------------
// Main: h = relu(A1@B1 + A2@B2 + b1) -> LDS tile (bf16, never to global).
// Epilogue: waves 0/1 compute p = h@Wa (bf16), q = h@Wb + bc2 (f32) via MFMA.
// MFMA layouts (HW-verified m89/m91): A: row=lane&15, k=quad*8+j;
// B: col=lane&15, k=quad*8+j; C/D: col=lane&15, row=quad*4+reg.

__global__ __launch_bounds__(256) void gemm1_kernel(
    const __bf16* __restrict__ A1, const __bf16* __restrict__ A2,
    const __bf16* __restrict__ B1T, const __bf16* __restrict__ B2T,
    const float* __restrict__ bias,
    const __bf16* __restrict__ WaT, const __bf16* __restrict__ WbT,
    const float* __restrict__ bc2,
    __bf16* __restrict__ pb, float* __restrict__ q, int M)
{
    __shared__ __align__(16) __bf16 tile[32][ZPAD];   // 16.5 KB

    int m0   = blockIdx.x * 32;
    int lane = threadIdx.x & 63;
    int wave = threadIdx.x >> 6;
    int l16  = lane & 15, quad = lane >> 4;

    f32x4 acc[2][4];
    #pragma unroll
    for (int a = 0; a < 2; ++a)
        #pragma unroll
        for (int b = 0; b < 4; ++b) acc[a][b] = (f32x4){0.f, 0.f, 0.f, 0.f};

    int arow[2];
    #pragma unroll
    for (int mt = 0; mt < 2; ++mt) {
        int r = m0 + mt * 16 + l16;
        arow[mt] = (r < M) ? r : (M - 1);
    }
    int nbase = wave * 64;

    for (int pass = 0; pass < 2; ++pass) {
        const __bf16* A  = pass ? A2 : A1;
        const __bf16* BT = pass ? B2T : B1T;
        #pragma unroll 2
        for (int kk = 0; kk < 8; ++kk) {
            int k0 = kk * 32 + quad * 8;
            bf16x8 af[2], bfm[4];
            #pragma unroll
            for (int mt = 0; mt < 2; ++mt)
                af[mt] = *(const bf16x8*)(A + (size_t)arow[mt] * FEAT + k0);
            #pragma unroll
            for (int nt = 0; nt < 4; ++nt)
                bfm[nt] = *(const bf16x8*)(BT + (size_t)(nbase + nt * 16 + l16) * FEAT + k0);
            #pragma unroll
            for (int mt = 0; mt < 2; ++mt)
                #pragma unroll
                for (int nt = 0; nt < 4; ++nt)
                    acc[mt][nt] = __builtin_amdgcn_mfma_f32_16x16x32_bf16(
                        af[mt], bfm[nt], acc[mt][nt], 0, 0, 0);
        }
    }

    // h tile (+bias, relu) -> LDS
    #pragma unroll
    for (int nt = 0; nt < 4; ++nt) {
        int col = nbase + nt * 16 + l16;
        float bv = bias[col];
        #pragma unroll
        for (int mt = 0; mt < 2; ++mt) {
            int lr = mt * 16 + quad * 4;
            #pragma unroll
            for (int r = 0; r < 4; ++r) {
                float v = acc[mt][nt][r] + bv;
                tile[lr + r][col] = (__bf16)(v > 0.f ? v : 0.f);
            }
        }
    }
    __syncthreads();

    // fused pq: waves 0/1, 16 rows each; A from LDS, B from L2-hot Wa/Wb
    if (wave < 2) {
        int lr = wave * 16 + l16;
        f32x4 ap = {0.f, 0.f, 0.f, 0.f}, aq = {0.f, 0.f, 0.f, 0.f};
        #pragma unroll
        for (int kk = 0; kk < 8; ++kk) {
            int k0 = kk * 32 + quad * 8;
            bf16x8 a  = *(const bf16x8*)(&tile[lr][k0]);
            bf16x8 ba = *(const bf16x8*)(WaT + (size_t)l16 * FEAT + k0);
            bf16x8 bb = *(const bf16x8*)(WbT + (size_t)l16 * FEAT + k0);
            ap = __builtin_amdgcn_mfma_f32_16x16x32_bf16(a, ba, ap, 0, 0, 0);
            aq = __builtin_amdgcn_mfma_f32_16x16x32_bf16(a, bb, aq, 0, 0, 0);
        }
        float qv = bc2[l16];
        #pragma unroll
        for (int r = 0; r < 4; ++r) {
            int row = m0 + wave * 16 + quad * 4 + r;
            if (row < M) {
                pb[(size_t)row * NCLS + l16] = (__bf16)ap[r];
                q[(size_t)row * NCLS + l16] = aq[r] + qv;
            }
        }
    }
}

// ---------------- agg_out: out = mean_j p[j] + q (16 feats) ----------------
// One wave per node; quad q takes bucket entries q, q+4, ... (2 in flight);
// lane l16 holds feature l16; shfl merge; quad 0 writes.

__global__ __launch_bounds__(256) void agg_out_kernel(
    const __bf16* __restrict__ pb, const float* __restrict__ q,
    const int* __restrict__ cnt, const unsigned short* __restrict__ bucket,
    float* __restrict__ out, int n)
{
    int wave = threadIdx.x >> 6;
    int node = blockIdx.x * 4 + wave;
    if (node >= n) return;
    int lane = threadIdx.x & 63;
    int quad = lane >> 4, l16 = lane & 15;
    int c = cnt[node];
    int deg = c < CAP ? c : CAP;
    const unsigned short* lst = bucket + node * CAP;

    float s0 = 0.f, s1 = 0.f;
    int e = quad;
    for (; e + 4 < deg; e += 8) {
        int j0 = lst[e], j1 = lst[e + 4];
        s0 += (float)pb[(size_t)j0 * NCLS + l16];
        s1 += (float)pb[(size_t)j1 * NCLS + l16];
    }
    if (e < deg) s0 += (float)pb[(size_t)lst[e] * NCLS + l16];

    float v = s0 + s1;
    v += __shfl_xor(v, 16, 64);
    v += __shfl_xor(v, 32, 64);

    if (quad == 0) {
        float inv = (c > 0) ? 1.0f / (float)c : 0.0f;
        out[(size_t)node * NCLS + l16] = v * inv + q[(size_t)node * NCLS + l16];
    }
}

// ---------------- launch ----------------

extern "C" void kernel_launch(void* const* d_in, const int* in_sizes, int n_in,
                              void* d_out, int out_size, void* d_ws, size_t ws_size,
                              hipStream_t stream) {
    const float* x   = (const float*)d_in[0];
    const int*   ei  = (const int*)d_in[1];
    const float* W1l = (const float*)d_in[2];
    const float* b1  = (const float*)d_in[3];
    const float* W1r = (const float*)d_in[4];
    const float* W2l = (const float*)d_in[5];
    const float* b2  = (const float*)d_in[6];
    const float* W2r = (const float*)d_in[7];
    const float* Wc  = (const float*)d_in[8];
    const float* bc  = (const float*)d_in[9];
    float* out = (float*)d_out;

    const int n = in_sizes[0] / FEAT;   // 20000
    const int E = in_sizes[1] / 2;      // 640000
    const int* srcp = ei;
    const int* dstp = ei + E;

    char* p = (char*)d_ws;
    auto alloc = [&](size_t bytes) { char* r = p; p += (bytes + 511) & ~511ull; return r; };
    int* cnt       = (int*)alloc((size_t)n * 4);
    unsigned short* bucket = (unsigned short*)alloc((size_t)n * CAP * 2);   // 5.12 MB
    __bf16* W1lT   = (__bf16*)alloc((size_t)FEAT * FEAT * 2);
    __bf16* W1rT   = (__bf16*)alloc((size_t)FEAT * FEAT * 2);
    __bf16* WaT    = (__bf16*)alloc((size_t)NCLS * FEAT * 2);
    __bf16* WbT    = (__bf16*)alloc((size_t)NCLS * FEAT * 2);
    float*  bc2    = (float*)alloc((size_t)NCLS * 4);
    __bf16* xb     = (__bf16*)alloc((size_t)n * FEAT * 2);
    unsigned char* x8 = (unsigned char*)alloc((size_t)n * FEAT);
    __bf16* aggb   = (__bf16*)alloc((size_t)n * FEAT * 2);
    __bf16* pb     = (__bf16*)alloc((size_t)n * NCLS * 2);
    float*  qb     = (float*)alloc((size_t)n * NCLS * 4);

    int n4 = n * FEAT / 4;
    int nb_cvt = (n4 + 255) / 256;          // 5000
    int nb_edge = (E + 511) / 512;          // 1250 (2 edges/thread)

    // cnt = 0 (80 KB)
    hipMemsetAsync(cnt, 0, (size_t)n * 4, stream);

    // combo: cvt + W1 transposes + Wa/Wb/bc2 + bucket fill
    combo_kernel<<<nb_cvt + 512 + 32 + 1 + nb_edge, 256, 0, stream>>>(
        x, W1l, W1r, W2l, W2r, Wc, b2, bc, srcp, dstp,
        xb, x8, W1lT, W1rT, WaT, WbT, bc2, cnt, bucket, n4, E, nb_cvt);

    // layer 1 + fused pq
    agg_fp8_kernel<<<(n + 3) / 4, 256, 0, stream>>>(x8, cnt, bucket, aggb, n);
    gemm1_kernel<<<(n + 31) / 32, 256, 0, stream>>>(aggb, xb, W1lT, W1rT, b1,
                                                    WaT, WbT, bc2, pb, qb, n);

    // layer-2 aggregation -> logits
    agg_out_kernel<<<(n + 3) / 4, 256, 0, stream>>>(pb, qb, cnt, bucket, out, n);
}